// Round 16
// baseline (859.783 us; speedup 1.0000x reference)
//
#include <hip/hip_runtime.h>

// 2-layer LSTM, B=2048, T=4096, IN=1, H=8, OUT=1, fp32.
//
// R22 = R21 (best, 842us) + BATCHED float4 output stores (lane 32, one
// dwordx4 per 4 bodies instead of 4 exec-masked scalar stores; saves
// ~2.3 insts/body of pure issue). R16 bundled this with MISALIGNED
// x-loads (the actual bug); the store side (op+4ck, 16B-aligned) was
// never cleanly tested. Loads stay scalar+clamped. Values and their
// op-index mapping are bit-identical to R21.
// Model (R8..R21): wall 493cy/iter; chain ~19 steps x ~8cy ~150cy;
// rest is per-wave issue (~200cy/wave/iter) at 82% SIMD busy ->
// chain-neutral inst cuts pay ~2x their count.
// Closed ledger: packed fp32 (half-rate), all-VALU ships (R11), desync
// (R17), misaligned float4 x-loads (R16), ship-far-h (R19), tree-dots
// (R20), R18 phase bug.
//
// Structure (R21): 1 seq/wave64, lane = L*32 + j*4 + g. ONE-hop ROW_ROR
// near-h gather (0x124/0x128/0x12C; weights indexed u[i] =
// (j&4)|((j+4-i)&3)). Spare-dot DS ship double-buffered across bodies:
// body(m) issues swz16(am2); body(m+1) forms d2 = an2_hold + s2p at its
// top, ships via bperm (full-body slack). s1 via permlane16_swap
// (on-chain, VALU). Gates pre-scaled by -log2e (g~ rows -2log2e);
// cs = c*N2L2E fold. Fills 0,1,2 zero L1; bodies 3,4 no store; steady
// m = 5..Tsz+4, store op[m-5] batched x4.

constexpr int Bsz = 2048;
constexpr int Tsz = 4096;

typedef int   v2i __attribute__((ext_vector_type(2)));
typedef float v4f __attribute__((ext_vector_type(4)));

template <int CTRL>
__device__ __forceinline__ float dpp(float v) {
    return __int_as_float(
        __builtin_amdgcn_mov_dpp(__float_as_int(v), CTRL, 0xF, 0xF, true));
}
// quad_perm bcast0..3 = 0x00,0x55,0xAA,0xFF; ROW_ROR:N = 0x120|N
// (dst[n] = src[(n-N)&15] within each 16-lane row)

// v[lane^16] via V_PERMLANE16_SWAP_B32 (VALU; verified bit-exact in R11).
__device__ __forceinline__ float xchg16(float v, bool hi16) {
    const int vi = __float_as_int(v);
    v2i p = __builtin_amdgcn_permlane16_swap(vi, vi, false, false);
    return __int_as_float(hi16 ? p.x : p.y);
}

__device__ __forceinline__ float swz16(float v) {
    // ds_swizzle bit mode, xor 0x10 within each 32-lane group
    return __int_as_float(
        __builtin_amdgcn_ds_swizzle(__float_as_int(v), (16 << 10) | 0x1f));
}

__device__ __forceinline__ float bperm(int addr, float v) {
    return __int_as_float(__builtin_amdgcn_ds_bpermute(addr, __float_as_int(v)));
}

__global__ void __launch_bounds__(256, 2) lstm2_bs(
    const float* __restrict__ x,      // [B, T]
    const float* __restrict__ Wih0,   // [32, 1]
    const float* __restrict__ Whh0,   // [32, 8]
    const float* __restrict__ bih0,   // [32]
    const float* __restrict__ bhh0,   // [32]
    const float* __restrict__ Wih1,   // [32, 8]
    const float* __restrict__ Whh1,   // [32, 8]
    const float* __restrict__ bih1,   // [32]
    const float* __restrict__ bhh1,   // [32]
    const float* __restrict__ Wlin,   // [1, 8]
    const float* __restrict__ blin,   // [1]
    float* __restrict__ out)          // [B, T]
{
    const int tid  = threadIdx.x;
    const int lane = tid & 63;
    const int g    = lane & 3;
    const int j    = (lane >> 2) & 7;
    const int L    = (lane >> 5) & 1;
    const int seq  = blockIdx.x * 4 + (tid >> 6);

    const int jm = j ^ 4;             // mirror lane's unit
    const int r  = g * 8 + j;         // own gate row
    const int rm = g * 8 + jm;        // mirror lane's gate row

    const bool hi16 = (lane & 16) != 0;

    const float NL2E  = -1.4426950408889634f;
    const float N2L2E = -2.8853900817779268f;
    const bool  isG   = (g == 2);
    const float ws    = isG ? N2L2E : NL2E;
    // c-scale fold: g~ lanes produce tanh(g)*N2L2E directly
    const float sA    = isG ? 2.0f * N2L2E : 1.0f;
    const float oA    = isG ? -N2L2E : 0.0f;

    const float* __restrict__ Whh = L ? Whh1 : Whh0;
    const float* __restrict__ bih = L ? bih1 : bih0;
    const float* __restrict__ bhh = L ? bhh1 : bhh0;

    // near-unit enumeration delivered by the 1-hop ROR gather:
    //   hn0 = h; hn1 = ROR:4 -> (j&4)|((j+3)&3); hn2 = ROR:8; hn3 = ROR:12
    int u[4];
    u[0] = j;
    u[1] = (j & 4) | ((j + 3) & 3);
    u[2] = (j & 4) | ((j + 2) & 3);
    u[3] = (j & 4) | ((j + 1) & 3);

    // near weights (own row) + mirror-row weights over units u[i]
    float wn1[4], wm1[4], wn2[4], wm2[4];
#pragma unroll
    for (int i = 0; i < 4; ++i) {
        const int k = u[i];
        wn1[i] = Whh[r * 8 + k] * ws;
        wm1[i] = Whh[rm * 8 + k] * ws;
        wn2[i] = L ? Wlin[k] : Wih1[r * 8 + k] * ws;
        wm2[i] = L ? Wlin[k] : Wih1[rm * 8 + k] * ws;
    }
    const float bias = (bih[r] + bhh[r]) * ws;
    const float wx   = L ? 0.0f : Wih0[r] * ws;
    const float b2   = L ? blin[0] : 0.0f;
    const float mL   = L ? 1.0f : 0.0f;
    const float keep = 1.0f - mL;
    const int  xaddr = (lane ^ 32) * 4;   // bpermute: cross layer halves

    const float* __restrict__ xp = x + (size_t)seq * Tsz;
    float* __restrict__ op       = out + (size_t)seq * Tsz;
    const bool storeLane = (lane == 32);

    float hn0 = 0.0f, hn1 = 0.0f, hn2 = 0.0f, hn3 = 0.0f;
    float cs = 0.0f;          // c' = c * N2L2E (scale-folded cell state)
    float recvP = 0.0f;       // bperm result in flight (1-body slack)
    float an2_hold = 0.0f;    // near spare dot from previous body
    float s2p = 0.0f;         // swz16 result in flight (1-body slack)

    auto body = [&](float xt, bool fill) -> float {
        // ---- top: consume previous body's in-flight DS results
        const float d2 = an2_hold + s2p;   // = full spare dot of h(m-2)
        const float rB = recvP;            // bperm(d2(m-1)) result
        recvP = bperm(xaddr, d2);          // issue; consumed next body
        const float t0 = fmaf(mL, rB, fmaf(wx, xt, bias));

        // -- mirror partials from entering hn (= h(m-1))
        float am2 = wm2[0] * hn0;
        am2 = fmaf(wm2[1], hn1, am2);
        am2 = fmaf(wm2[2], hn2, am2);
        am2 = fmaf(wm2[3], hn3, am2);
        s2p = swz16(am2);                  // issue; consumed next body

        float am1 = wm1[0] * hn0;
        am1 = fmaf(wm1[1], hn1, am1);
        am1 = fmaf(wm1[2], hn2, am1);
        am1 = fmaf(wm1[3], hn3, am1);
        const float s1 = xchg16(am1, hi16);   // ON-CHAIN: VALU permlane swap

        // -- near dots
        float an1 = fmaf(wn1[0], hn0, t0);
        an1 = fmaf(wn1[1], hn1, an1);
        an1 = fmaf(wn1[2], hn2, an1);
        an1 = fmaf(wn1[3], hn3, an1);
        float an2 = fmaf(wn2[0], hn0, b2);
        an2 = fmaf(wn2[1], hn1, an2);
        an2 = fmaf(wn2[2], hn2, an2);
        an2 = fmaf(wn2[3], hn3, an2);
        an2_hold = an2;

        // -- z: near (incl. recvB via t0) + far(ship)
        const float z = an1 + s1;

        // -- activation (pre-scaled): sig, or tanh*N2L2E for g~ lanes
        float a = fmaf(sA,
                       __builtin_amdgcn_rcpf(1.0f + __builtin_amdgcn_exp2f(z)),
                       oA);
        const float gi = dpp<0x00>(a);
        const float gf = dpp<0x55>(a);
        const float gG = dpp<0xAA>(a);        // = tanh(g)*N2L2E (pre-scaled)
        const float go = dpp<0xFF>(a);
        const float go2 = go + go;            // off-critical
        cs = fmaf(gf, cs, gi * gG);           // c' = c*N2L2E
        const float e  = __builtin_amdgcn_exp2f(cs);
        const float rr = __builtin_amdgcn_rcpf(1.0f + e);
        float h = fmaf(go2, rr, -go);         // = go*(2*rr-1)

        if (fill) { h *= keep; cs *= keep; }  // keep L1 state at zero

        // -- near-h gather for next iter: ONE-hop ROW_ROR (3 parallel DPPs)
        hn0 = h;                              // unit j
        hn1 = dpp<0x124>(h);                  // ROW_ROR:4
        hn2 = dpp<0x128>(h);                  // ROW_ROR:8
        hn3 = dpp<0x12C>(h);                  // ROW_ROR:12

        return d2;                            // proj value (valid on L1 lanes)
    };

    // ---- prologue: bodies 0,1,2 zero L1 state; 3,4 run free, no store
    body(xp[0], true);
    body(xp[1], true);
    body(xp[2], true);
    body(xp[3], false);
    body(xp[4], false);

    // ---- steady, unrolled x4: m = 5 .. Tsz+4, store op[m-5] batched x4
    float xc[4];
#pragma unroll
    for (int q = 0; q < 4; ++q) xc[q] = xp[5 + q];   // x(5..8)
    for (int ck = 0; ck < Tsz / 4; ++ck) {
        const int base = 5 + 4 * ck;
        float xf[4];
#pragma unroll
        for (int q = 0; q < 4; ++q) {
            int idx = base + 4 + q;
            idx = (idx < Tsz) ? idx : (Tsz - 1);
            xf[q] = xp[idx];                 // prefetch next chunk (clamped)
        }
        v4f d4;
#pragma unroll
        for (int q = 0; q < 4; ++q)
            d4[q] = body(xc[q], false);      // op[m-5] values
        if (storeLane) *(v4f*)(op + 4 * ck) = d4;   // 16B-aligned dwordx4
#pragma unroll
        for (int q = 0; q < 4; ++q) xc[q] = xf[q];
    }
}

extern "C" void kernel_launch(void* const* d_in, const int* in_sizes, int n_in,
                              void* d_out, int out_size, void* d_ws, size_t ws_size,
                              hipStream_t stream) {
    const float* x    = (const float*)d_in[0];
    const float* Wih0 = (const float*)d_in[1];
    const float* Whh0 = (const float*)d_in[2];
    const float* bih0 = (const float*)d_in[3];
    const float* bhh0 = (const float*)d_in[4];
    const float* Wih1 = (const float*)d_in[5];
    const float* Whh1 = (const float*)d_in[6];
    const float* bih1 = (const float*)d_in[7];
    const float* bhh1 = (const float*)d_in[8];
    const float* Wlin = (const float*)d_in[9];
    const float* blin = (const float*)d_in[10];
    float* out = (float*)d_out;

    dim3 grid(Bsz / 4);   // 4 waves/block, 1 seq/wave -> 512 blocks, 2048 waves
    dim3 block(256);
    hipLaunchKernelGGL(lstm2_bs, grid, block, 0, stream,
                       x, Wih0, Whh0, bih0, bhh0,
                       Wih1, Whh1, bih1, bhh1, Wlin, blin, out);
}